// Round 9
// baseline (975.389 us; speedup 1.0000x reference)
//
#include <hip/hip_runtime.h>

typedef unsigned short u16;
typedef __attribute__((ext_vector_type(2))) unsigned int u32x2;
typedef __attribute__((ext_vector_type(4))) unsigned int u32x4;
typedef __attribute__((ext_vector_type(4))) float f32x4;
typedef __attribute__((ext_vector_type(8))) short bf16x8;

__device__ __forceinline__ float bf2f(u16 u) {
    union { unsigned int i; float f; } v; v.i = ((unsigned int)u) << 16; return v.f;
}
__device__ __forceinline__ u16 f2bf(float f) {
    union { float f; unsigned int i; } v; v.f = f;
    unsigned int x = v.i;
    return (u16)((x + 0x7fffu + ((x >> 16) & 1u)) >> 16);
}
__device__ __forceinline__ unsigned int pack2(float a, float b) {
    return (unsigned int)f2bf(a) | ((unsigned int)f2bf(b) << 16);
}
// truncation split: h+l == a exactly to ~2^-16 rel; lo compensates hi trunc.
__device__ __forceinline__ void tsplit2(float a, float b,
                                        unsigned int& h, unsigned int& l) {
    unsigned int ua = __float_as_uint(a), ub = __float_as_uint(b);
    float fa = __uint_as_float(ua & 0xffff0000u);
    float fb = __uint_as_float(ub & 0xffff0000u);
    h = (ua >> 16) | (ub & 0xffff0000u);
    float la = a - fa, lb = b - fb;
    l = (__float_as_uint(la) >> 16) | (__float_as_uint(lb) & 0xffff0000u);
}

__device__ __forceinline__ f32x4 MFMA(bf16x8 a, bf16x8 b, f32x4 c) {
    return __builtin_amdgcn_mfma_f32_16x16x32_bf16(a, b, c, 0, 0, 0);
}

// ---------------------------------------------------------------------------
// kprep: WxTb = bf16(Wx); WfxTg = bf16(Wfx);
//        WsP[h][gfc][lane][j] = invt_h * Wslice[gfc*16+(lane&15)][d(lane>>4,j)]
//          with d(l4,j) = (j>>2)*16 + l4*4 + (j&3)   (k-permuted B2 fragment)
//        bslv[h][g] = bslice[g] * invt_h
// ---------------------------------------------------------------------------
__global__ __launch_bounds__(256) void kprep(
    const float* __restrict__ Wx, const float* __restrict__ Wfx,
    const float* __restrict__ Wslice, const float* __restrict__ bslice,
    const float* __restrict__ temperature,
    u16* __restrict__ WxTb, u16* __restrict__ WfxTg,
    u16* __restrict__ WsP, float* __restrict__ bslv)
{
    const int gidx = blockIdx.x * 256 + threadIdx.x;
    if (gidx < 65536) {
        WxTb[gidx] = f2bf(Wx[gidx]);
    } else if (gidx < 131072) {
        const int i = gidx - 65536;
        WfxTg[i] = f2bf(Wfx[i]);
    } else if (gidx < 147456) {
        const int i = gidx - 131072;
        const int h = i >> 11;
        const int rem = i & 2047;
        const int gfc = rem >> 9;
        const int l = (rem >> 3) & 63;
        const int j = i & 7;
        const int g = gfc * 16 + (l & 15);
        const int d = ((j >> 2) << 4) + ((l >> 4) << 2) + (j & 3);
        float tc = fminf(fmaxf(temperature[h], 0.1f), 5.0f);
        WsP[i] = f2bf(Wslice[g * 32 + d] / tc);
    } else if (gidx < 147968) {
        const int i = gidx - 147456;
        const int h = i >> 6, g = i & 63;
        float tc = fminf(fmaxf(temperature[h], 0.1f), 5.0f);
        bslv[i] = bslice[g] / tc;
    }
}

// ---------------------------------------------------------------------------
// kAB v7: rank-32 logits + register-A/B x fragments. Block = 2 heads (hp),
// 512 thr, wave = (hl, tq). 64-token tiles, grid 1024 (bid = c*4+hp).
// LDS 80KB: [0,32K) WxTb rows (64), [32K,64K) WfxT rows (64), [64K,80K) img.
// GEMM phase barrier-free; 2 barriers/tile (image region only).
// ---------------------------------------------------------------------------
__global__ __launch_bounds__(512, 2) void kAB(
    const float* __restrict__ x, const u16* __restrict__ WxTb,
    const u16* __restrict__ WfxTg, const u16* __restrict__ WsP,
    const float* __restrict__ bx, const float* __restrict__ bfx,
    const float* __restrict__ bslv,
    u16* __restrict__ swg, float* __restrict__ pst, float* __restrict__ pnorm)
{
    __shared__ char lds[81920];
    const int tid  = threadIdx.x;
    const int wv   = tid >> 6;
    const int lane = tid & 63;
    const int l15  = lane & 15;
    const int l4   = lane >> 4;
    const int hl   = wv >> 2;
    const int tq   = wv & 3;

    const int bid  = blockIdx.x;
    const int c    = bid >> 2;
    const int hp   = bid & 3;
    const int head = hp * 2 + hl;

    // stage weights: rows 0..63 = WxTb (2 heads x 32 d), 64..127 = WfxT
    for (int u = tid; u < 4096; u += 512) {
        const int row = u >> 5, seg = u & 31;
        const u16* src;
        if (row < 64)
            src = WxTb + ((size_t)(hp * 2 + (row >> 5)) * 32 + (row & 31)) * 256 + seg * 8;
        else {
            const int rr = row - 64;
            src = WfxTg + ((size_t)(hp * 2 + (rr >> 5)) * 32 + (rr & 31)) * 256 + seg * 8;
        }
        *(u32x4*)(lds + ((row * 512 + seg * 16) ^ ((row & 7) << 4))) = *(const u32x4*)src;
    }

    // per-wave constants
    bf16x8 wsp[4];
    #pragma unroll
    for (int g = 0; g < 4; ++g)
        wsp[g] = *(const bf16x8*)(WsP + (size_t)head * 2048 + g * 512 + lane * 8);
    float bsl[4], bfv[2], bxv[2][4];
    #pragma unroll
    for (int g = 0; g < 4; ++g) bsl[g] = bslv[head * 64 + g * 16 + l15];
    #pragma unroll
    for (int fc = 0; fc < 2; ++fc) bfv[fc] = bfx[head * 32 + fc * 16 + l15];
    #pragma unroll
    for (int fc = 0; fc < 2; ++fc)
        #pragma unroll
        for (int r = 0; r < 4; ++r)
            bxv[fc][r] = bx[head * 32 + fc * 16 + l4 * 4 + r];

    f32x4 stacc[2][4];
    #pragma unroll
    for (int i = 0; i < 2; ++i)
        #pragma unroll
        for (int j = 0; j < 4; ++j) stacc[i][j] = (f32x4){0.f, 0.f, 0.f, 0.f};
    float nacc[4] = {0.f, 0.f, 0.f, 0.f};

    const int cnt = 12 + (c < 53 ? 1 : 0);     // 256*12 + 53 = 3125 tiles
    const long tb = (long)c * 12 + (c < 53 ? c : 53);

    const int rowoff = (tq * 16 + l15) * 256 + l4 * 8;   // lane's x offset

    f32x4 pf[16];
    {
        const float* xp = x + (size_t)(tb * 64) * 256 + rowoff;
        #pragma unroll
        for (int ks = 0; ks < 8; ++ks) {
            pf[2 * ks]     = *(const f32x4*)(xp + ks * 32);
            pf[2 * ks + 1] = *(const f32x4*)(xp + ks * 32 + 4);
        }
    }
    __syncthreads();   // weights staged

    for (int t = 0; t < cnt; ++t) {
        const long tok0 = (tb + t) * 64;

        // ---- GEMM phase (barrier-free): fx + x_mid^T over K=256 ----
        f32x4 acc1[2], accF[2];
        #pragma unroll
        for (int fc = 0; fc < 2; ++fc) {
            acc1[fc] = (f32x4){0.f, 0.f, 0.f, 0.f};
            accF[fc] = (f32x4){0.f, 0.f, 0.f, 0.f};
        }
        #pragma unroll
        for (int ks = 0; ks < 8; ++ks) {
            union { u32x4 u; bf16x8 b; } bh, bl;
            {
                f32x4 p0 = pf[2 * ks], p1 = pf[2 * ks + 1];
                unsigned int h0, l0, h1, l1, h2, l2, h3, l3;
                tsplit2(p0[0], p0[1], h0, l0);
                tsplit2(p0[2], p0[3], h1, l1);
                tsplit2(p1[0], p1[1], h2, l2);
                tsplit2(p1[2], p1[3], h3, l3);
                bh.u = (u32x4){h0, h1, h2, h3};
                bl.u = (u32x4){l0, l1, l2, l3};
            }
            const int kb = ks * 64 + l4 * 16;
            bf16x8 awx[2], awf[2];
            #pragma unroll
            for (int fc = 0; fc < 2; ++fc) {
                const int r1 = hl * 32 + fc * 16 + l15;
                awx[fc] = *(const bf16x8*)(lds + ((r1 * 512 + kb) ^ ((r1 & 7) << 4)));
                const int r2 = 64 + hl * 32 + fc * 16 + l15;
                awf[fc] = *(const bf16x8*)(lds + ((r2 * 512 + kb) ^ ((r2 & 7) << 4)));
            }
            #pragma unroll
            for (int fc = 0; fc < 2; ++fc) {
                accF[fc] = MFMA(bh.b, awf[fc], accF[fc]);   // fx: A=x, B=Wfx
                acc1[fc] = MFMA(awx[fc], bh.b, acc1[fc]);   // x_mid^T: A=Wx, B=x
                acc1[fc] = MFMA(awx[fc], bl.b, acc1[fc]);
            }
        }
        // fx trunc-bias correction + bias
        #pragma unroll
        for (int fc = 0; fc < 2; ++fc)
            #pragma unroll
            for (int r = 0; r < 4; ++r)
                accF[fc][r] = accF[fc][r] * 1.001953125f + bfv[fc];

        // ---- GEMM2: logits = (x_mid + bx) @ WsP (K=32, in-register A) ----
        union { u32x4 u; bf16x8 b; } a2h, a2l;
        {
            unsigned int ah0, al0, ah1, al1, ah2, al2, ah3, al3;
            float m0 = acc1[0][0] + bxv[0][0];
            float m1 = acc1[0][1] + bxv[0][1];
            float m2 = acc1[0][2] + bxv[0][2];
            float m3 = acc1[0][3] + bxv[0][3];
            tsplit2(m0, m1, ah0, al0);
            tsplit2(m2, m3, ah1, al1);
            float n0 = acc1[1][0] + bxv[1][0];
            float n1 = acc1[1][1] + bxv[1][1];
            float n2 = acc1[1][2] + bxv[1][2];
            float n3 = acc1[1][3] + bxv[1][3];
            tsplit2(n0, n1, ah2, al2);
            tsplit2(n2, n3, ah3, al3);
            a2h.u = (u32x4){ah0, ah1, ah2, ah3};
            a2l.u = (u32x4){al0, al1, al2, al3};
        }
        f32x4 accL[4];
        #pragma unroll
        for (int g = 0; g < 4; ++g) {
            accL[g] = (f32x4){bsl[g], bsl[g], bsl[g], bsl[g]};
            accL[g] = MFMA(a2h.b, wsp[g], accL[g]);
            accL[g] = MFMA(a2l.b, wsp[g], accL[g]);
        }

        // prefetch next x tile (lands under softmax/P4/P5/copyout)
        if (t + 1 < cnt) {
            const float* xn = x + (size_t)(tok0 + 64) * 256 + rowoff;
            #pragma unroll
            for (int ks = 0; ks < 8; ++ks) {
                pf[2 * ks]     = *(const f32x4*)(xn + ks * 32);
                pf[2 * ks + 1] = *(const f32x4*)(xn + ks * 32 + 4);
            }
        }

        // ---- softmax over 64 g (4 g-frags x 16 lanes) ----
        float mrow[4], srow4[4];
        #pragma unroll
        for (int r = 0; r < 4; ++r)
            mrow[r] = fmaxf(fmaxf(accL[0][r], accL[1][r]), fmaxf(accL[2][r], accL[3][r]));
        #pragma unroll
        for (int d = 1; d <= 8; d <<= 1)
            #pragma unroll
            for (int r = 0; r < 4; ++r)
                mrow[r] = fmaxf(mrow[r], __shfl_xor(mrow[r], d));
        #pragma unroll
        for (int r = 0; r < 4; ++r) {
            float e0 = __expf(accL[0][r] - mrow[r]);
            float e1 = __expf(accL[1][r] - mrow[r]);
            float e2 = __expf(accL[2][r] - mrow[r]);
            float e3 = __expf(accL[3][r] - mrow[r]);
            accL[0][r] = e0; accL[1][r] = e1; accL[2][r] = e2; accL[3][r] = e3;
            srow4[r] = e0 + e1 + e2 + e3;
        }
        #pragma unroll
        for (int d = 1; d <= 8; d <<= 1)
            #pragma unroll
            for (int r = 0; r < 4; ++r)
                srow4[r] += __shfl_xor(srow4[r], d);
        #pragma unroll
        for (int r = 0; r < 4; ++r) {
            const float inv = 1.0f / srow4[r];
            float e0 = accL[0][r] * inv, e1 = accL[1][r] * inv;
            float e2 = accL[2][r] * inv, e3 = accL[3][r] * inv;
            accL[0][r] = e0; accL[1][r] = e1; accL[2][r] = e2; accL[3][r] = e3;
            nacc[0] += e0; nacc[1] += e1; nacc[2] += e2; nacc[3] += e3;
        }

        __syncthreads();   // A: image region free (prev copy-out complete)

        // ---- P4: pack sw + write swizzled image [64 tok][128 col] ----
        unsigned int pL[4][2];
        #pragma unroll
        for (int fc = 0; fc < 4; ++fc) {
            u16 w0 = f2bf(accL[fc][0]), w1 = f2bf(accL[fc][1]);
            u16 w2 = f2bf(accL[fc][2]), w3 = f2bf(accL[fc][3]);
            pL[fc][0] = (unsigned int)w0 | ((unsigned int)w1 << 16);
            pL[fc][1] = (unsigned int)w2 | ((unsigned int)w3 << 16);
            const int col2 = (hl * 64 + fc * 16 + l15) * 2;
            #pragma unroll
            for (int r = 0; r < 4; ++r) {
                const int tok = tq * 16 + l4 * 4 + r;
                const u16 val = (r == 0) ? w0 : (r == 1) ? w1 : (r == 2) ? w2 : w3;
                *(u16*)(lds + 65536 + ((tok * 256 + col2) ^ ((tok & 7) << 4))) = val;
            }
        }

        // ---- P5: slice_token partial (reg-only, K zero-padded) ----
        unsigned int pF[2][2];
        #pragma unroll
        for (int fc = 0; fc < 2; ++fc) {
            pF[fc][0] = pack2(accF[fc][0], accF[fc][1]);
            pF[fc][1] = pack2(accF[fc][2], accF[fc][3]);
        }
        #pragma unroll
        for (int mt2 = 0; mt2 < 2; ++mt2) {
            union { u32x4 u; bf16x8 b; } a;
            a.u = (u32x4){pF[mt2][0], pF[mt2][1], 0u, 0u};
            #pragma unroll
            for (int nt = 0; nt < 4; ++nt) {
                union { u32x4 u; bf16x8 b; } bb;
                bb.u = (u32x4){pL[nt][0], pL[nt][1], 0u, 0u};
                stacc[mt2][nt] = MFMA(a.b, bb.b, stacc[mt2][nt]);
            }
        }

        __syncthreads();   // B: image complete

        // ---- copy-out image -> global ----
        #pragma unroll
        for (int q = 0; q < 2; ++q) {
            const int slot = tid * 2 + q;
            const int tok = slot >> 4, sg = slot & 15;
            u32x4 v = *(const u32x4*)(lds + 65536 + ((tok * 256 + sg * 16) ^ ((tok & 7) << 4)));
            __builtin_nontemporal_store(v,
                (u32x4*)(swg + (size_t)(tok0 + tok) * 512 + hp * 128 + sg * 8));
        }
    }

    // ---- epilogue: cross-wave (tq) reduction ----
    __syncthreads();
    float* sst = (float*)lds;               // weights region dead: [8][2048]
    float* nst = (float*)(lds + 65536);     // image region: [8][64]
    #pragma unroll
    for (int mt2 = 0; mt2 < 2; ++mt2)
        #pragma unroll
        for (int nt = 0; nt < 4; ++nt)
            #pragma unroll
            for (int r = 0; r < 4; ++r)
                sst[wv * 2048 + (mt2 * 16 + l4 * 4 + r) * 64 + nt * 16 + l15] = stacc[mt2][nt][r];
    #pragma unroll
    for (int fc = 0; fc < 4; ++fc) {
        float v = nacc[fc];
        v += __shfl_xor(v, 16); v += __shfl_xor(v, 32);
        if (l4 == 0) nst[wv * 64 + fc * 16 + l15] = v;
    }
    __syncthreads();
    for (int i = tid; i < 4096; i += 512) {
        const int hl2 = i >> 11, e = i & 2047;
        float s = sst[(hl2 * 4 + 0) * 2048 + e] + sst[(hl2 * 4 + 1) * 2048 + e]
                + sst[(hl2 * 4 + 2) * 2048 + e] + sst[(hl2 * 4 + 3) * 2048 + e];
        __builtin_nontemporal_store(s,
            pst + ((size_t)(hp * 2 + hl2) * 256 + c) * 2048 + e);
    }
    if (tid < 128) {
        const int hl2 = tid >> 6, g = tid & 63;
        float s = nst[(hl2 * 4 + 0) * 64 + g] + nst[(hl2 * 4 + 1) * 64 + g]
                + nst[(hl2 * 4 + 2) * 64 + g] + nst[(hl2 * 4 + 3) * 64 + g];
        pnorm[((size_t)(hp * 2 + hl2) * 256 + c) * 64 + g] = s;
    }
}

// ---------------------------------------------------------------------------
// kC1: blocks 0..127: stn[16384] = sum_chunk pst; blocks 128..131: norm[512]
// ---------------------------------------------------------------------------
__global__ __launch_bounds__(256) void kC1(
    const float* __restrict__ pst, const float* __restrict__ pnorm,
    float* __restrict__ stn, float* __restrict__ norm)
{
    __shared__ float red[256];
    const int tid  = threadIdx.x;
    const int half = tid >> 7;
    const int li   = tid & 127;
    if (blockIdx.x < 128) {
        const int o  = blockIdx.x * 128 + li;
        const int h  = o >> 11, oo = o & 2047;
        float s = 0.f;
        for (int b = half * 128; b < half * 128 + 128; ++b)
            s += __builtin_nontemporal_load(pst + ((size_t)h * 256 + b) * 2048 + oo);
        red[tid] = s;
        __syncthreads();
        if (!half) stn[o] = red[li] + red[li + 128];
    } else {
        const int o = (blockIdx.x - 128) * 128 + li;
        const int h = o >> 6, g = o & 63;
        float s = 0.f;
        for (int b = half * 128; b < half * 128 + 128; ++b)
            s += pnorm[((size_t)h * 256 + b) * 64 + g];
        red[tid] = s;
        __syncthreads();
        if (!half) norm[o] = red[li] + red[li + 128];
    }
}

// ---------------------------------------------------------------------------
// kattn: tiny per-head attention over 64 slice tokens
// ---------------------------------------------------------------------------
__global__ __launch_bounds__(64) void kattn(
    const float* __restrict__ stn, const float* __restrict__ norm,
    const float* __restrict__ Wq, const float* __restrict__ Wk,
    const float* __restrict__ Wv, float* __restrict__ os)
{
    __shared__ float kl[2048], vl[2048];
    const int h = blockIdx.x, g = threadIdx.x;
    const float ng = norm[h * 64 + g] + 1e-5f;
    float s[32];
    #pragma unroll
    for (int d = 0; d < 32; ++d) s[d] = stn[h * 2048 + d * 64 + g] / ng;
    float q[32];
    #pragma unroll
    for (int e = 0; e < 32; ++e) {
        float aq = 0.f, ak = 0.f, av = 0.f;
        #pragma unroll
        for (int d = 0; d < 32; ++d) {
            aq += s[d] * Wq[e * 32 + d];
            ak += s[d] * Wk[e * 32 + d];
            av += s[d] * Wv[e * 32 + d];
        }
        q[e] = aq; kl[g * 32 + e] = ak; vl[g * 32 + e] = av;
    }
    __syncthreads();
    float p[64];
    float mx = -1e30f;
    const float scale = 0.17677669529663689f;
    #pragma unroll
    for (int kk = 0; kk < 64; ++kk) {
        float a = 0.f;
        #pragma unroll
        for (int e = 0; e < 32; ++e) a += q[e] * kl[kk * 32 + e];
        a *= scale; p[kk] = a; mx = fmaxf(mx, a);
    }
    float sum = 0.f;
    #pragma unroll
    for (int kk = 0; kk < 64; ++kk) { p[kk] = __expf(p[kk] - mx); sum += p[kk]; }
    const float inv = 1.0f / sum;
    #pragma unroll
    for (int d = 0; d < 32; ++d) {
        float a = 0.f;
        #pragma unroll
        for (int kk = 0; kk < 64; ++kk) a += p[kk] * inv * vl[kk * 32 + d];
        os[h * 2048 + g * 32 + d] = a;
    }
}

// ---------------------------------------------------------------------------
// kD2: Wc2T[co][hg] = sum_d os[h,g,d] * Wout[co, h*32+d]   (bf16)
// ---------------------------------------------------------------------------
__global__ __launch_bounds__(64) void kD2(
    const float* __restrict__ os, const float* __restrict__ Wout,
    u16* __restrict__ Wc2T)
{
    const int co = blockIdx.x;
    for (int rep = 0; rep < 8; ++rep) {
        const int hg = rep * 64 + threadIdx.x;
        const int h = hg >> 6, g = hg & 63;
        float s = 0.f;
        #pragma unroll
        for (int d = 0; d < 32; ++d)
            s += os[h * 2048 + g * 32 + d] * Wout[co * 256 + h * 32 + d];
        Wc2T[co * 512 + hg] = f2bf(s);
    }
}

// ---------------------------------------------------------------------------
// kE v3: out = sw @ Wc2T^T + bout. Grid 512, 64KB single buffer,
// launch_bounds(512,4) -> 2 blocks/CU (4 waves/SIMD). B from L2 per ks.
// ---------------------------------------------------------------------------
__global__ __launch_bounds__(512, 4) void kE(
    const u16* __restrict__ swg, const u16* __restrict__ Wc2T,
    const float* __restrict__ bout, float* __restrict__ y)
{
    __shared__ char lds[65536];
    const int tid  = threadIdx.x;
    const int w    = tid >> 6;
    const int lane = tid & 63;
    const int l15  = lane & 15;
    const int l4   = lane >> 4;
    const int aswz = (l15 & 7) << 4;

    const int bid = blockIdx.x;
    const int cnt = 6 + (bid < 53 ? 1 : 0);      // 512*6 + 53 = 3125 tiles
    const long tb = (long)bid * 6 + (bid < 53 ? bid : 53);

    const u16* Bp = Wc2T + (size_t)(w * 32 + l15) * 512 + l4 * 8;
    const float b0 = bout[w * 32 + l15], b1 = bout[w * 32 + 16 + l15];

    const int row = tid >> 3, seg = tid & 7;
    const int sbase = row * 1024 + seg * 128;
    const int sswz  = (row & 7) << 4;

    u32x4 pf[8];
    {
        const u32x4* sp = (const u32x4*)(swg + (size_t)(tb * 64 + row) * 512 + seg * 64);
        #pragma unroll
        for (int c = 0; c < 8; ++c) pf[c] = __builtin_nontemporal_load(sp + c);
    }

    for (int t = 0; t < cnt; ++t) {
        const long tok0 = (tb + t) * 64;

        #pragma unroll
        for (int c = 0; c < 8; ++c)
            *(u32x4*)(lds + ((sbase + c * 16) ^ sswz)) = pf[c];
        __syncthreads();

        if (t + 1 < cnt) {
            const u32x4* sp = (const u32x4*)(swg + (size_t)(tok0 + 64 + row) * 512 + seg * 64);
            #pragma unroll
            for (int c = 0; c < 8; ++c) pf[c] = __builtin_nontemporal_load(sp + c);
        }

        f32x4 acc[4][2];
        #pragma unroll
        for (int mt = 0; mt < 4; ++mt) {
            acc[mt][0] = (f32x4){b0, b0, b0, b0};
            acc[mt][1] = (f32x4){b1, b1, b1, b1};
        }

        #pragma unroll
        for (int ks = 0; ks < 16; ++ks) {
            bf16x8 bf0 = *(const bf16x8*)(Bp + ks * 32);
            bf16x8 bf1 = *(const bf16x8*)(Bp + (size_t)16 * 512 + ks * 32);
            bf16x8 a[4];
            #pragma unroll
            for (int mt = 0; mt < 4; ++mt)
                a[mt] = *(const bf16x8*)(lds + (mt * 16 + l15) * 1024 + ((ks * 64 + l4 * 16) ^ aswz));
            #pragma unroll
            for (int mt = 0; mt < 4; ++mt) {
                acc[mt][0] = MFMA(a[mt], bf0, acc[mt][0]);
                acc[mt][1] = MFMA(a[mt], bf1, acc[mt][1]);
            }
        }

        #pragma unroll
        for (int mt = 0; mt < 4; ++mt)
            #pragma unroll
            for (int fc = 0; fc < 2; ++fc)
                #pragma unroll
                for (int r = 0; r < 4; ++r) {
                    const long n = tok0 + mt * 16 + l4 * 4 + r;
                    __builtin_nontemporal_store(acc[mt][fc][r],
                        y + (size_t)n * 256 + w * 32 + fc * 16 + l15);
                }
        __syncthreads();
    }
}

// ---------------------------------------------------------------------------
extern "C" void kernel_launch(void* const* d_in, const int* in_sizes, int n_in,
                              void* d_out, int out_size, void* d_ws, size_t ws_size,
                              hipStream_t stream) {
    const float* x       = (const float*)d_in[0];
    const float* Wx      = (const float*)d_in[1];
    const float* bx      = (const float*)d_in[2];
    const float* Wfx     = (const float*)d_in[3];
    const float* bfx     = (const float*)d_in[4];
    const float* Wslice  = (const float*)d_in[5];
    const float* bslice  = (const float*)d_in[6];
    const float* Wq      = (const float*)d_in[7];
    const float* Wk      = (const float*)d_in[8];
    const float* Wv      = (const float*)d_in[9];
    const float* Wout    = (const float*)d_in[10];
    const float* bout    = (const float*)d_in[11];
    const float* temp    = (const float*)d_in[12];

    char* wsb = (char*)d_ws;
    u16*   sw    = (u16*)(wsb);                      // 204,800,000 B
    float* pst   = (float*)(wsb + 204800000);        //  16,777,216 B
    float* pnorm = (float*)(wsb + 238354432);        //     524,288 B
    u16*   WxTb  = (u16*)(wsb + 239403008);          //     131,072 B
    u16*   WfxTg = (u16*)(wsb + 239534080);          //     131,072 B
    u16*   WsP   = (u16*)(wsb + 239665152);          //      32,768 B
    float* bslv  = (float*)(wsb + 239697920);        //       2,048 B
    u16*   Wc2T  = (u16*)(wsb + 239798272);          //     262,144 B
    float* os    = (float*)(wsb + 240060416);        //      65,536 B
    float* stn   = (float*)(wsb + 240125952);        //      65,536 B
    float* norm  = (float*)(wsb + 240191488);        //       2,048 B
    float* y     = (float*)d_out;

    kprep<<<578, 256, 0, stream>>>(Wx, Wfx, Wslice, bslice, temp, WxTb, WfxTg, WsP, bslv);
    kAB<<<1024, 512, 0, stream>>>(x, WxTb, WfxTg, WsP, bx, bfx, bslv, sw, pst, pnorm);
    kC1<<<132, 256, 0, stream>>>(pst, pnorm, stn, norm);
    kattn<<<8, 64, 0, stream>>>(stn, norm, Wq, Wk, Wv, os);
    kD2<<<256, 64, 0, stream>>>(os, Wout, Wc2T);
    kE<<<512, 512, 0, stream>>>(sw, Wc2T, bout, y);
}

// Round 10
// 563.514 us; speedup vs baseline: 1.7309x; 1.7309x over previous
//
#include <hip/hip_runtime.h>

typedef unsigned short u16;
typedef __attribute__((ext_vector_type(2))) unsigned int u32x2;
typedef __attribute__((ext_vector_type(4))) unsigned int u32x4;
typedef __attribute__((ext_vector_type(4))) float f32x4;
typedef __attribute__((ext_vector_type(8))) short bf16x8;

__device__ __forceinline__ float bf2f(u16 u) {
    union { unsigned int i; float f; } v; v.i = ((unsigned int)u) << 16; return v.f;
}
__device__ __forceinline__ u16 f2bf(float f) {
    union { float f; unsigned int i; } v; v.f = f;
    unsigned int x = v.i;
    return (u16)((x + 0x7fffu + ((x >> 16) & 1u)) >> 16);
}
__device__ __forceinline__ unsigned int pack2(float a, float b) {
    return (unsigned int)f2bf(a) | ((unsigned int)f2bf(b) << 16);
}
__device__ __forceinline__ void split2(float a, float b, unsigned int& h, unsigned int& l) {
    u16 ha = f2bf(a), hb = f2bf(b);
    u16 la = f2bf(a - bf2f(ha)), lb = f2bf(b - bf2f(hb));
    h = (unsigned int)ha | ((unsigned int)hb << 16);
    l = (unsigned int)la | ((unsigned int)lb << 16);
}

__device__ __forceinline__ f32x4 MFMA(bf16x8 a, bf16x8 b, f32x4 c) {
    return __builtin_amdgcn_mfma_f32_16x16x32_bf16(a, b, c, 0, 0, 0);
}

// ---------------------------------------------------------------------------
// kprep: Wcomb[hg][k] = invt_h * sum_d Wslice[g,d]*Wx[h*32+d,k]  (bf16)
//        bcomb[hg]    = invt_h * (sum_d Wslice[g,d]*bx[h*32+d] + bslice[g])
//        WfxT = bf16(Wfx)
// ---------------------------------------------------------------------------
__global__ __launch_bounds__(256) void kprep(
    const float* __restrict__ Wx, const float* __restrict__ bx,
    const float* __restrict__ Wfx, const float* __restrict__ Wslice,
    const float* __restrict__ bslice, const float* __restrict__ temperature,
    u16* __restrict__ Wcomb, float* __restrict__ bcomb, u16* __restrict__ WfxT)
{
    const int gidx = blockIdx.x * 256 + threadIdx.x;
    if (gidx < 131072) {
        const int hg = gidx >> 8, k = gidx & 255;
        const int h = hg >> 6, g = hg & 63;
        float tc = fminf(fmaxf(temperature[h], 0.1f), 5.0f);
        const float invt = 1.0f / tc;
        float s = 0.f;
        #pragma unroll
        for (int d = 0; d < 32; ++d) s += Wslice[g * 32 + d] * Wx[(h * 32 + d) * 256 + k];
        Wcomb[hg * 256 + k] = f2bf(s * invt);
    } else if (gidx < 131072 + 65536) {
        const int i = gidx - 131072;
        WfxT[i] = f2bf(Wfx[i]);
    } else if (gidx < 131072 + 65536 + 512) {
        const int hg = gidx - 131072 - 65536;
        const int h = hg >> 6, g = hg & 63;
        float tc = fminf(fmaxf(temperature[h], 0.1f), 5.0f);
        float s = bslice[g];
        #pragma unroll
        for (int d = 0; d < 32; ++d) s += Wslice[g * 32 + d] * bx[h * 32 + d];
        bcomb[hg] = s / tc;
    }
}

// ---------------------------------------------------------------------------
// kAB (R7 verbatim, measured 329us): WEIGHTS IN LDS. Block = 2 heads (hp),
// 512 thr (8 waves): wave v: hl=v>>2, tq=v&3 (16 tokens of 64-tile).
// LDS 160KB: [0,96K) weights, [96K,128K) x-hi, [128K,160K) x-lo / sw image.
// ---------------------------------------------------------------------------
#define LDS_XH 98304
#define LDS_XL 131072
__global__ __launch_bounds__(512, 2) void kAB(
    const float* __restrict__ x, const u16* __restrict__ Wcomb,
    const float* __restrict__ bcomb, const u16* __restrict__ WfxT,
    const float* __restrict__ bfx,
    u16* __restrict__ swg, float* __restrict__ pst, float* __restrict__ pnorm)
{
    __shared__ char lds[163840];
    const int tid  = threadIdx.x;
    const int wv   = tid >> 6;
    const int lane = tid & 63;
    const int l15  = lane & 15;
    const int l4   = lane >> 4;
    const int hl   = wv >> 2;
    const int tq   = wv & 3;

    const int bid = blockIdx.x;
    const int c   = bid >> 2;
    const int hp  = bid & 3;
    const int head = hp * 2 + hl;

    for (int u = tid; u < 6144; u += 512) {
        const int row = u >> 5, seg = u & 31;
        const u16* src = (row < 128)
            ? Wcomb + ((size_t)hp * 128 + row) * 256 + seg * 8
            : WfxT  + ((size_t)hp * 64 + (row - 128)) * 256 + seg * 8;
        u32x4 v = *(const u32x4*)src;
        *(u32x4*)(lds + ((row * 512 + seg * 16) ^ ((row & 7) << 4))) = v;
    }

    float bc[4], bfv[2];
    #pragma unroll
    for (int fc = 0; fc < 4; ++fc) bc[fc] = bcomb[head * 64 + fc * 16 + l15];
    #pragma unroll
    for (int fc = 0; fc < 2; ++fc) bfv[fc] = bfx[head * 32 + fc * 16 + l15];

    f32x4 stacc[2][4];
    #pragma unroll
    for (int i = 0; i < 2; ++i)
        #pragma unroll
        for (int j = 0; j < 4; ++j) stacc[i][j] = (f32x4){0.f, 0.f, 0.f, 0.f};
    float nacc[4] = {0.f, 0.f, 0.f, 0.f};

    const int cnt = 12 + (c < 53 ? 1 : 0);
    const long tb = (long)c * 12 + (c < 53 ? c : 53);

    const int row = tid >> 3, seg = tid & 7;
    const int xswz = (row & 7) << 4;

    f32x4 pf[8];
    #pragma unroll
    for (int i = 0; i < 8; ++i)
        pf[i] = *(const f32x4*)(x + (size_t)(tb * 64 + row) * 256 + i * 32 + seg * 4);

    const int xrow  = tq * 16 + l15;
    const int xoff  = xrow * 512;
    const int xkey  = (xrow & 7) << 4;
    const int bwrow0 = hl * 64 + l15;
    const int bfrow0 = 128 + hl * 32 + l15;

    for (int t = 0; t < cnt; ++t) {
        const long tok0 = (tb + t) * 64;

        __syncthreads();
        #pragma unroll
        for (int i = 0; i < 8; ++i) {
            unsigned int h0, l0, h1, l1;
            split2(pf[i][0], pf[i][1], h0, l0);
            split2(pf[i][2], pf[i][3], h1, l1);
            const int a = (row * 512 + i * 64 + seg * 8) ^ xswz;
            *(u32x2*)(lds + LDS_XH + a) = (u32x2){h0, h1};
            *(u32x2*)(lds + LDS_XL + a) = (u32x2){l0, l1};
        }
        __syncthreads();

        f32x4 accF[2], accL[4];
        #pragma unroll
        for (int fc = 0; fc < 2; ++fc) accF[fc] = (f32x4){bfv[fc], bfv[fc], bfv[fc], bfv[fc]};
        #pragma unroll
        for (int fc = 0; fc < 4; ++fc) accL[fc] = (f32x4){bc[fc], bc[fc], bc[fc], bc[fc]};
        #pragma unroll
        for (int ks = 0; ks < 8; ++ks) {
            const int kb = ks * 64 + l4 * 16;
            bf16x8 ah = *(const bf16x8*)(lds + LDS_XH + ((xoff + kb) ^ xkey));
            bf16x8 al = *(const bf16x8*)(lds + LDS_XL + ((xoff + kb) ^ xkey));
            bf16x8 bw[4], bfF[2];
            #pragma unroll
            for (int fc = 0; fc < 4; ++fc) {
                const int r2 = bwrow0 + fc * 16;
                bw[fc] = *(const bf16x8*)(lds + ((r2 * 512 + kb) ^ ((r2 & 7) << 4)));
            }
            #pragma unroll
            for (int fc = 0; fc < 2; ++fc) {
                const int r2 = bfrow0 + fc * 16;
                bfF[fc] = *(const bf16x8*)(lds + ((r2 * 512 + kb) ^ ((r2 & 7) << 4)));
            }
            #pragma unroll
            for (int fc = 0; fc < 2; ++fc) accF[fc] = MFMA(ah, bfF[fc], accF[fc]);
            #pragma unroll
            for (int fc = 0; fc < 4; ++fc) {
                accL[fc] = MFMA(ah, bw[fc], accL[fc]);
                accL[fc] = MFMA(al, bw[fc], accL[fc]);
            }
        }

        if (t + 1 < cnt) {
            #pragma unroll
            for (int i = 0; i < 8; ++i)
                pf[i] = *(const f32x4*)(x + (size_t)(tok0 + 64 + row) * 256 + i * 32 + seg * 4);
        }

        float mrow[4], srow4[4];
        #pragma unroll
        for (int r = 0; r < 4; ++r)
            mrow[r] = fmaxf(fmaxf(accL[0][r], accL[1][r]), fmaxf(accL[2][r], accL[3][r]));
        #pragma unroll
        for (int d = 1; d <= 8; d <<= 1)
            #pragma unroll
            for (int r = 0; r < 4; ++r)
                mrow[r] = fmaxf(mrow[r], __shfl_xor(mrow[r], d));
        #pragma unroll
        for (int r = 0; r < 4; ++r) {
            float e0 = __expf(accL[0][r] - mrow[r]);
            float e1 = __expf(accL[1][r] - mrow[r]);
            float e2 = __expf(accL[2][r] - mrow[r]);
            float e3 = __expf(accL[3][r] - mrow[r]);
            accL[0][r] = e0; accL[1][r] = e1; accL[2][r] = e2; accL[3][r] = e3;
            srow4[r] = e0 + e1 + e2 + e3;
        }
        #pragma unroll
        for (int d = 1; d <= 8; d <<= 1)
            #pragma unroll
            for (int r = 0; r < 4; ++r)
                srow4[r] += __shfl_xor(srow4[r], d);
        #pragma unroll
        for (int r = 0; r < 4; ++r) {
            const float inv = 1.0f / srow4[r];
            float e0 = accL[0][r] * inv, e1 = accL[1][r] * inv;
            float e2 = accL[2][r] * inv, e3 = accL[3][r] * inv;
            accL[0][r] = e0; accL[1][r] = e1; accL[2][r] = e2; accL[3][r] = e3;
            nacc[0] += e0; nacc[1] += e1; nacc[2] += e2; nacc[3] += e3;
        }

        __syncthreads();

        unsigned int pL[4][2];
        #pragma unroll
        for (int fc = 0; fc < 4; ++fc) {
            u16 w0 = f2bf(accL[fc][0]), w1 = f2bf(accL[fc][1]);
            u16 w2 = f2bf(accL[fc][2]), w3 = f2bf(accL[fc][3]);
            pL[fc][0] = (unsigned int)w0 | ((unsigned int)w1 << 16);
            pL[fc][1] = (unsigned int)w2 | ((unsigned int)w3 << 16);
            const int col2 = (hl * 64 + fc * 16 + l15) * 2;
            #pragma unroll
            for (int r = 0; r < 4; ++r) {
                const int tok = tq * 16 + l4 * 4 + r;
                const u16 val = (r == 0) ? w0 : (r == 1) ? w1 : (r == 2) ? w2 : w3;
                *(u16*)(lds + LDS_XL + ((tok * 256 + col2) ^ ((tok & 7) << 4))) = val;
            }
        }

        unsigned int pF[2][2];
        #pragma unroll
        for (int fc = 0; fc < 2; ++fc) {
            pF[fc][0] = pack2(accF[fc][0], accF[fc][1]);
            pF[fc][1] = pack2(accF[fc][2], accF[fc][3]);
        }
        #pragma unroll
        for (int mt2 = 0; mt2 < 2; ++mt2) {
            union { u32x4 u; bf16x8 b; } a;
            a.u = (u32x4){pF[mt2][0], pF[mt2][1], 0u, 0u};
            #pragma unroll
            for (int nt = 0; nt < 4; ++nt) {
                union { u32x4 u; bf16x8 b; } bb;
                bb.u = (u32x4){pL[nt][0], pL[nt][1], 0u, 0u};
                stacc[mt2][nt] = MFMA(a.b, bb.b, stacc[mt2][nt]);
            }
        }

        __syncthreads();

        #pragma unroll
        for (int q = 0; q < 2; ++q) {
            const int slot = tid * 2 + q;
            const int tok = slot >> 4, sg = slot & 15;
            u32x4 v = *(const u32x4*)(lds + LDS_XL + ((tok * 256 + sg * 16) ^ ((tok & 7) << 4)));
            __builtin_nontemporal_store(v,
                (u32x4*)(swg + (size_t)(tok0 + tok) * 512 + hp * 128 + sg * 8));
        }
    }

    // epilogue: cross-wave (tq) reduction of stacc / nacc
    __syncthreads();
    float* sst = (float*)(lds + LDS_XH);
    float* nst = (float*)lds;
    #pragma unroll
    for (int mt2 = 0; mt2 < 2; ++mt2)
        #pragma unroll
        for (int nt = 0; nt < 4; ++nt)
            #pragma unroll
            for (int r = 0; r < 4; ++r)
                sst[wv * 2048 + (mt2 * 16 + l4 * 4 + r) * 64 + nt * 16 + l15] = stacc[mt2][nt][r];
    #pragma unroll
    for (int fc = 0; fc < 4; ++fc) {
        float v = nacc[fc];
        v += __shfl_xor(v, 16); v += __shfl_xor(v, 32);
        if (l4 == 0) nst[wv * 64 + fc * 16 + l15] = v;
    }
    __syncthreads();
    for (int i = tid; i < 4096; i += 512) {
        const int hl2 = i >> 11, e = i & 2047;
        float s = sst[(hl2 * 4 + 0) * 2048 + e] + sst[(hl2 * 4 + 1) * 2048 + e]
                + sst[(hl2 * 4 + 2) * 2048 + e] + sst[(hl2 * 4 + 3) * 2048 + e];
        __builtin_nontemporal_store(s,
            pst + ((size_t)(hp * 2 + hl2) * 256 + c) * 2048 + e);
    }
    if (tid < 128) {
        const int hl2 = tid >> 6, g = tid & 63;
        float s = nst[(hl2 * 4 + 0) * 64 + g] + nst[(hl2 * 4 + 1) * 64 + g]
                + nst[(hl2 * 4 + 2) * 64 + g] + nst[(hl2 * 4 + 3) * 64 + g];
        pnorm[((size_t)(hp * 2 + hl2) * 256 + c) * 64 + g] = s;
    }
}

// ---------------------------------------------------------------------------
// kC1: blocks 0..127: stn[16384] = sum_chunk pst; blocks 128..131: norm[512]
// ---------------------------------------------------------------------------
__global__ __launch_bounds__(256) void kC1(
    const float* __restrict__ pst, const float* __restrict__ pnorm,
    float* __restrict__ stn, float* __restrict__ norm)
{
    __shared__ float red[256];
    const int tid  = threadIdx.x;
    const int half = tid >> 7;
    const int li   = tid & 127;
    if (blockIdx.x < 128) {
        const int o  = blockIdx.x * 128 + li;
        const int h  = o >> 11, oo = o & 2047;
        float s = 0.f;
        for (int b = half * 128; b < half * 128 + 128; ++b)
            s += __builtin_nontemporal_load(pst + ((size_t)h * 256 + b) * 2048 + oo);
        red[tid] = s;
        __syncthreads();
        if (!half) stn[o] = red[li] + red[li + 128];
    } else {
        const int o = (blockIdx.x - 128) * 128 + li;
        const int h = o >> 6, g = o & 63;
        float s = 0.f;
        for (int b = half * 128; b < half * 128 + 128; ++b)
            s += pnorm[((size_t)h * 256 + b) * 64 + g];
        red[tid] = s;
        __syncthreads();
        if (!half) norm[o] = red[li] + red[li + 128];
    }
}

// ---------------------------------------------------------------------------
// kattn: tiny per-head attention over 64 slice tokens
// ---------------------------------------------------------------------------
__global__ __launch_bounds__(64) void kattn(
    const float* __restrict__ stn, const float* __restrict__ norm,
    const float* __restrict__ Wq, const float* __restrict__ Wk,
    const float* __restrict__ Wv, float* __restrict__ os)
{
    __shared__ float kl[2048], vl[2048];
    const int h = blockIdx.x, g = threadIdx.x;
    const float ng = norm[h * 64 + g] + 1e-5f;
    float s[32];
    #pragma unroll
    for (int d = 0; d < 32; ++d) s[d] = stn[h * 2048 + d * 64 + g] / ng;
    float q[32];
    #pragma unroll
    for (int e = 0; e < 32; ++e) {
        float aq = 0.f, ak = 0.f, av = 0.f;
        #pragma unroll
        for (int d = 0; d < 32; ++d) {
            aq += s[d] * Wq[e * 32 + d];
            ak += s[d] * Wk[e * 32 + d];
            av += s[d] * Wv[e * 32 + d];
        }
        q[e] = aq; kl[g * 32 + e] = ak; vl[g * 32 + e] = av;
    }
    __syncthreads();
    float p[64];
    float mx = -1e30f;
    const float scale = 0.17677669529663689f;
    #pragma unroll
    for (int kk = 0; kk < 64; ++kk) {
        float a = 0.f;
        #pragma unroll
        for (int e = 0; e < 32; ++e) a += q[e] * kl[kk * 32 + e];
        a *= scale; p[kk] = a; mx = fmaxf(mx, a);
    }
    float sum = 0.f;
    #pragma unroll
    for (int kk = 0; kk < 64; ++kk) { p[kk] = __expf(p[kk] - mx); sum += p[kk]; }
    const float inv = 1.0f / sum;
    #pragma unroll
    for (int d = 0; d < 32; ++d) {
        float a = 0.f;
        #pragma unroll
        for (int kk = 0; kk < 64; ++kk) a += p[kk] * inv * vl[kk * 32 + d];
        os[h * 2048 + g * 32 + d] = a;
    }
}

// ---------------------------------------------------------------------------
// kD2: Wc2T[co][hg] = sum_d os[h,g,d] * Wout[co, h*32+d]   (bf16)
// ---------------------------------------------------------------------------
__global__ __launch_bounds__(64) void kD2(
    const float* __restrict__ os, const float* __restrict__ Wout,
    u16* __restrict__ Wc2T)
{
    const int co = blockIdx.x;
    for (int rep = 0; rep < 8; ++rep) {
        const int hg = rep * 64 + threadIdx.x;
        const int h = hg >> 6, g = hg & 63;
        float s = 0.f;
        #pragma unroll
        for (int d = 0; d < 32; ++d)
            s += os[h * 2048 + g * 32 + d] * Wout[co * 256 + h * 32 + d];
        Wc2T[co * 512 + hg] = f2bf(s);
    }
}

// ---------------------------------------------------------------------------
// kE v4: out = sw @ Wc2T^T + bout. 32-token tiles, grid 512, B hoisted to
// 128 VGPR under (512,2) [cap 256 — no starvation]. LDS 64KB = 32K sw stage
// + 32K y-image (scalar->LDS XOR-swizzled, copy-out as full-line f32x4 nt).
// 2 barriers/tile, 2 blocks/CU.
// ---------------------------------------------------------------------------
__global__ __launch_bounds__(512, 2) void kE(
    const u16* __restrict__ swg, const u16* __restrict__ Wc2T,
    const float* __restrict__ bout, float* __restrict__ y)
{
    __shared__ char lds[65536];
    const int tid  = threadIdx.x;
    const int w    = tid >> 6;
    const int lane = tid & 63;
    const int l15  = lane & 15;
    const int l4   = lane >> 4;
    const int aswz = (l15 & 7) << 4;

    const int bid = blockIdx.x;
    const int cnt = 12 + (bid < 106 ? 1 : 0);    // 512*12 + 106 = 6250 tiles
    const long tb = (long)bid * 12 + (bid < 106 ? bid : 106);

    // hoist B: 16 ks x 2 fc x 16B = 128 VGPR (L2-hot, shared by all blocks)
    bf16x8 Breg[16][2];
    #pragma unroll
    for (int ks = 0; ks < 16; ++ks)
        #pragma unroll
        for (int fc = 0; fc < 2; ++fc)
            Breg[ks][fc] = *(const bf16x8*)(Wc2T +
                (size_t)(w * 32 + fc * 16 + l15) * 512 + ks * 32 + l4 * 8);

    const float b0 = bout[w * 32 + l15], b1 = bout[w * 32 + 16 + l15];

    // staging slots: slot = tid + k*512 over 2048 (32 rows x 64 x 16B)
    u32x4 pf[4];
    #pragma unroll
    for (int k = 0; k < 4; ++k) {
        const int slot = tid + k * 512;
        const int srow = slot >> 6, ss = slot & 63;
        pf[k] = __builtin_nontemporal_load(
            (const u32x4*)(swg + (size_t)(tb * 32 + srow) * 512 + ss * 8));
    }

    for (int t = 0; t < cnt; ++t) {
        const long tok0 = (tb + t) * 32;

        // stage sw tile (swizzled rows)
        #pragma unroll
        for (int k = 0; k < 4; ++k) {
            const int slot = tid + k * 512;
            const int srow = slot >> 6, ss = slot & 63;
            *(u32x4*)(lds + ((srow * 1024 + ss * 16) ^ ((srow & 7) << 4))) = pf[k];
        }
        __syncthreads();   // barrier 1: stage visible

        // prefetch next tile
        if (t + 1 < cnt) {
            #pragma unroll
            for (int k = 0; k < 4; ++k) {
                const int slot = tid + k * 512;
                const int srow = slot >> 6, ss = slot & 63;
                pf[k] = __builtin_nontemporal_load(
                    (const u32x4*)(swg + (size_t)(tok0 + 32 + srow) * 512 + ss * 8));
            }
        }

        f32x4 acc[2][2];
        #pragma unroll
        for (int mt = 0; mt < 2; ++mt) {
            acc[mt][0] = (f32x4){b0, b0, b0, b0};
            acc[mt][1] = (f32x4){b1, b1, b1, b1};
        }

        #pragma unroll
        for (int ks = 0; ks < 16; ++ks) {
            bf16x8 a[2];
            #pragma unroll
            for (int mt = 0; mt < 2; ++mt)
                a[mt] = *(const bf16x8*)(lds + (mt * 16 + l15) * 1024 + ((ks * 64 + l4 * 16) ^ aswz));
            #pragma unroll
            for (int mt = 0; mt < 2; ++mt) {
                acc[mt][0] = MFMA(a[mt], Breg[ks][0], acc[mt][0]);
                acc[mt][1] = MFMA(a[mt], Breg[ks][1], acc[mt][1]);
            }
        }

        // y image: scalar f32 -> LDS (XOR swizzle on 16B granule)
        #pragma unroll
        for (int mt = 0; mt < 2; ++mt)
            #pragma unroll
            for (int fc = 0; fc < 2; ++fc)
                #pragma unroll
                for (int r = 0; r < 4; ++r) {
                    const int tok = mt * 16 + l4 * 4 + r;
                    const int col = w * 32 + fc * 16 + l15;
                    *(float*)(lds + 32768 + ((tok * 1024 + col * 4) ^ ((tok & 7) << 4))) =
                        acc[mt][fc][r];
                }
        __syncthreads();   // barrier 2: image complete (also guards region A reuse)

        // copy-out y: full-line coalesced f32x4 nt stores
        #pragma unroll
        for (int k = 0; k < 4; ++k) {
            const int slot = tid + k * 512;
            const int yrow = slot >> 6, ys = slot & 63;
            u32x4 v = *(const u32x4*)(lds + 32768 + ((yrow * 1024 + ys * 16) ^ ((yrow & 7) << 4)));
            __builtin_nontemporal_store(v,
                (u32x4*)(y + (size_t)(tok0 + yrow) * 256 + ys * 4));
        }
    }
}

// ---------------------------------------------------------------------------
extern "C" void kernel_launch(void* const* d_in, const int* in_sizes, int n_in,
                              void* d_out, int out_size, void* d_ws, size_t ws_size,
                              hipStream_t stream) {
    const float* x       = (const float*)d_in[0];
    const float* Wx      = (const float*)d_in[1];
    const float* bx      = (const float*)d_in[2];
    const float* Wfx     = (const float*)d_in[3];
    const float* bfx     = (const float*)d_in[4];
    const float* Wslice  = (const float*)d_in[5];
    const float* bslice  = (const float*)d_in[6];
    const float* Wq      = (const float*)d_in[7];
    const float* Wk      = (const float*)d_in[8];
    const float* Wv      = (const float*)d_in[9];
    const float* Wout    = (const float*)d_in[10];
    const float* bout    = (const float*)d_in[11];
    const float* temp    = (const float*)d_in[12];

    char* wsb = (char*)d_ws;
    u16*   sw    = (u16*)(wsb);                      // 204,800,000 B
    float* pst   = (float*)(wsb + 204800000);        //  16,777,216 B
    float* pnorm = (float*)(wsb + 238354432);        //     524,288 B
    u16*   Wcomb = (u16*)(wsb + 239403008);          //     262,144 B
    float* bcomb = (float*)(wsb + 239665152);        //       2,048 B
    u16*   WfxT  = (u16*)(wsb + 239667200);          //     131,072 B
    u16*   Wc2T  = (u16*)(wsb + 239798272);          //     262,144 B
    float* os    = (float*)(wsb + 240060416);        //      65,536 B
    float* stn   = (float*)(wsb + 240125952);        //      65,536 B
    float* norm  = (float*)(wsb + 240191488);        //       2,048 B
    float* y     = (float*)d_out;

    kprep<<<770, 256, 0, stream>>>(Wx, bx, Wfx, Wslice, bslice, temp, Wcomb, bcomb, WfxT);
    kAB<<<1024, 512, 0, stream>>>(x, Wcomb, bcomb, WfxT, bfx, sw, pst, pnorm);
    kC1<<<132, 256, 0, stream>>>(pst, pnorm, stn, norm);
    kattn<<<8, 64, 0, stream>>>(stn, norm, Wq, Wk, Wv, os);
    kD2<<<256, 64, 0, stream>>>(os, Wout, Wc2T);
    kE<<<512, 512, 0, stream>>>(sw, Wc2T, bout, y);
}

// Round 11
// 539.027 us; speedup vs baseline: 1.8095x; 1.0454x over previous
//
#include <hip/hip_runtime.h>

typedef unsigned short u16;
typedef __attribute__((ext_vector_type(2))) unsigned int u32x2;
typedef __attribute__((ext_vector_type(4))) unsigned int u32x4;
typedef __attribute__((ext_vector_type(4))) float f32x4;
typedef __attribute__((ext_vector_type(8))) short bf16x8;

__device__ __forceinline__ float bf2f(u16 u) {
    union { unsigned int i; float f; } v; v.i = ((unsigned int)u) << 16; return v.f;
}
__device__ __forceinline__ u16 f2bf(float f) {
    union { float f; unsigned int i; } v; v.f = f;
    unsigned int x = v.i;
    return (u16)((x + 0x7fffu + ((x >> 16) & 1u)) >> 16);
}
__device__ __forceinline__ unsigned int pack2(float a, float b) {
    return (unsigned int)f2bf(a) | ((unsigned int)f2bf(b) << 16);
}
// RTNE split (hi unbiased; hi+lo ~exact)
__device__ __forceinline__ void split2(float a, float b, unsigned int& h, unsigned int& l) {
    u16 ha = f2bf(a), hb = f2bf(b);
    u16 la = f2bf(a - bf2f(ha)), lb = f2bf(b - bf2f(hb));
    h = (unsigned int)ha | ((unsigned int)hb << 16);
    l = (unsigned int)la | ((unsigned int)lb << 16);
}
// truncation split (hi+lo exact sum; hi biased low — only for hi+lo uses)
__device__ __forceinline__ void tsplit2(float a, float b,
                                        unsigned int& h, unsigned int& l) {
    unsigned int ua = __float_as_uint(a), ub = __float_as_uint(b);
    float fa = __uint_as_float(ua & 0xffff0000u);
    float fb = __uint_as_float(ub & 0xffff0000u);
    h = (ua >> 16) | (ub & 0xffff0000u);
    float la = a - fa, lb = b - fb;
    l = (__float_as_uint(la) >> 16) | (__float_as_uint(lb) & 0xffff0000u);
}

__device__ __forceinline__ f32x4 MFMA(bf16x8 a, bf16x8 b, f32x4 c) {
    return __builtin_amdgcn_mfma_f32_16x16x32_bf16(a, b, c, 0, 0, 0);
}

// ---------------------------------------------------------------------------
// kprep (R9-validated): WxTb = bf16(Wx); WfxTg = bf16(Wfx);
//   WsP[h][gfc][lane][j] = invt_h * Wslice[gfc*16+(lane&15)][(j>>2)*16+(lane>>4)*4+(j&3)]
//   bslv[h][g] = bslice[g] * invt_h
// ---------------------------------------------------------------------------
__global__ __launch_bounds__(256) void kprep(
    const float* __restrict__ Wx, const float* __restrict__ Wfx,
    const float* __restrict__ Wslice, const float* __restrict__ bslice,
    const float* __restrict__ temperature,
    u16* __restrict__ WxTb, u16* __restrict__ WfxTg,
    u16* __restrict__ WsP, float* __restrict__ bslv)
{
    const int gidx = blockIdx.x * 256 + threadIdx.x;
    if (gidx < 65536) {
        WxTb[gidx] = f2bf(Wx[gidx]);
    } else if (gidx < 131072) {
        const int i = gidx - 65536;
        WfxTg[i] = f2bf(Wfx[i]);
    } else if (gidx < 147456) {
        const int i = gidx - 131072;
        const int h = i >> 11;
        const int rem = i & 2047;
        const int gfc = rem >> 9;
        const int l = (rem >> 3) & 63;
        const int j = i & 7;
        const int g = gfc * 16 + (l & 15);
        const int d = ((j >> 2) << 4) + ((l >> 4) << 2) + (j & 3);
        float tc = fminf(fmaxf(temperature[h], 0.1f), 5.0f);
        WsP[i] = f2bf(Wslice[g * 32 + d] / tc);
    } else if (gidx < 147968) {
        const int i = gidx - 147456;
        const int h = i >> 6, g = i & 63;
        float tc = fminf(fmaxf(temperature[h], 0.1f), 5.0f);
        bslv[i] = bslice[g] / tc;
    }
}

// ---------------------------------------------------------------------------
// kAB v8: rank-32 logits (R9-validated numerics) + R7 coalesced LDS staging.
// Block = 2 heads (hp), 512 thr, wave = (hl, tq). 64-token tiles, grid 1024.
// LDS 144KB: [0,64K) weights (64 Wx rows + 64 Wfx rows, XOR-swizzled),
//   [64K,96K) x-hi, [96K,128K) x-lo, [128K,144K) sw image (own region).
// One ah/al read feeds fx-A AND xmid-B (identical lane maps). 2 barriers/tile.
// ---------------------------------------------------------------------------
#define LDS_XH 65536
#define LDS_XL 98304
#define LDS_IM 131072
__global__ __launch_bounds__(512, 2) void kAB(
    const float* __restrict__ x, const u16* __restrict__ WxTb,
    const u16* __restrict__ WfxTg, const u16* __restrict__ WsP,
    const float* __restrict__ bx, const float* __restrict__ bfx,
    const float* __restrict__ bslv,
    u16* __restrict__ swg, float* __restrict__ pst, float* __restrict__ pnorm)
{
    __shared__ char lds[147456];
    const int tid  = threadIdx.x;
    const int wv   = tid >> 6;
    const int lane = tid & 63;
    const int l15  = lane & 15;
    const int l4   = lane >> 4;
    const int hl   = wv >> 2;
    const int tq   = wv & 3;

    const int bid  = blockIdx.x;
    const int c    = bid >> 2;
    const int hp   = bid & 3;
    const int head = hp * 2 + hl;

    // stage weights once: rows 0..63 = Wx (2 heads x 32 e), 64..127 = Wfx
    for (int u = tid; u < 4096; u += 512) {
        const int row = u >> 5, seg = u & 31;
        const u16* src;
        if (row < 64)
            src = WxTb + ((size_t)(hp * 2 + (row >> 5)) * 32 + (row & 31)) * 256 + seg * 8;
        else {
            const int rr = row - 64;
            src = WfxTg + ((size_t)(hp * 2 + (rr >> 5)) * 32 + (rr & 31)) * 256 + seg * 8;
        }
        *(u32x4*)(lds + ((row * 512 + seg * 16) ^ ((row & 7) << 4))) = *(const u32x4*)src;
    }

    // per-wave constants
    bf16x8 wsp[4];
    #pragma unroll
    for (int g = 0; g < 4; ++g)
        wsp[g] = *(const bf16x8*)(WsP + (size_t)head * 2048 + g * 512 + lane * 8);
    float bsl[4], bfv[2], bxv[2][4];
    #pragma unroll
    for (int g = 0; g < 4; ++g) bsl[g] = bslv[head * 64 + g * 16 + l15];
    #pragma unroll
    for (int fc = 0; fc < 2; ++fc) bfv[fc] = bfx[head * 32 + fc * 16 + l15];
    #pragma unroll
    for (int fc = 0; fc < 2; ++fc)
        #pragma unroll
        for (int r = 0; r < 4; ++r)
            bxv[fc][r] = bx[head * 32 + fc * 16 + l4 * 4 + r];

    f32x4 stacc[2][4];
    #pragma unroll
    for (int i = 0; i < 2; ++i)
        #pragma unroll
        for (int j = 0; j < 4; ++j) stacc[i][j] = (f32x4){0.f, 0.f, 0.f, 0.f};
    float nacc[4] = {0.f, 0.f, 0.f, 0.f};

    const int cnt = 12 + (c < 53 ? 1 : 0);     // 256*12 + 53 = 3125 tiles
    const long tb = (long)c * 12 + (c < 53 ? c : 53);

    // x staging: row = tid>>3 (0..63), seg = tid&7
    const int row = tid >> 3, seg = tid & 7;
    const int xswz = (row & 7) << 4;

    f32x4 pf[8];
    #pragma unroll
    for (int i = 0; i < 8; ++i)
        pf[i] = *(const f32x4*)(x + (size_t)(tb * 64 + row) * 256 + i * 32 + seg * 4);

    const int xrow = tq * 16 + l15;
    const int xoff = xrow * 512;
    const int xkey = (xrow & 7) << 4;

    for (int t = 0; t < cnt; ++t) {
        const long tok0 = (tb + t) * 64;

        // ---- stage x hi/lo (RTNE split: hi feeds fx alone) ----
        #pragma unroll
        for (int i = 0; i < 8; ++i) {
            unsigned int h0, l0, h1, l1;
            split2(pf[i][0], pf[i][1], h0, l0);
            split2(pf[i][2], pf[i][3], h1, l1);
            const int a = (row * 512 + i * 64 + seg * 8) ^ xswz;
            *(u32x2*)(lds + LDS_XH + a) = (u32x2){h0, h1};
            *(u32x2*)(lds + LDS_XL + a) = (u32x2){l0, l1};
        }
        __syncthreads();   // B1: staging visible (and prev copy-out done)

        // ---- GEMM1: fx (x as A) + x_mid^T (x as B), shared ah/al reads ----
        f32x4 acc1[2], accF[2];
        #pragma unroll
        for (int fc = 0; fc < 2; ++fc) {
            accF[fc] = (f32x4){bfv[fc], bfv[fc], bfv[fc], bfv[fc]};
            acc1[fc] = (f32x4){0.f, 0.f, 0.f, 0.f};
        }
        #pragma unroll
        for (int ks = 0; ks < 8; ++ks) {
            const int kb = ks * 64 + l4 * 16;
            bf16x8 ah = *(const bf16x8*)(lds + LDS_XH + ((xoff + kb) ^ xkey));
            bf16x8 al = *(const bf16x8*)(lds + LDS_XL + ((xoff + kb) ^ xkey));
            bf16x8 awx[2], awf[2];
            #pragma unroll
            for (int fc = 0; fc < 2; ++fc) {
                const int r1 = hl * 32 + fc * 16 + l15;
                awx[fc] = *(const bf16x8*)(lds + ((r1 * 512 + kb) ^ ((r1 & 7) << 4)));
                const int r2 = 64 + r1;
                awf[fc] = *(const bf16x8*)(lds + ((r2 * 512 + kb) ^ ((r2 & 7) << 4)));
            }
            #pragma unroll
            for (int fc = 0; fc < 2; ++fc) {
                accF[fc] = MFMA(ah, awf[fc], accF[fc]);      // fx
                acc1[fc] = MFMA(awx[fc], ah, acc1[fc]);      // x_mid^T hi
                acc1[fc] = MFMA(awx[fc], al, acc1[fc]);      // x_mid^T lo
            }
        }

        // prefetch next x tile (lands under GEMM2/softmax/P4/P5/copyout)
        if (t + 1 < cnt) {
            #pragma unroll
            for (int i = 0; i < 8; ++i)
                pf[i] = *(const f32x4*)(x + (size_t)(tok0 + 64 + row) * 256 + i * 32 + seg * 4);
        }

        // ---- GEMM2: logits = (x_mid + bx) @ WsP  (K=32, register A) ----
        union { u32x4 u; bf16x8 b; } a2h, a2l;
        {
            unsigned int h0, l0, h1, l1, h2, l2, h3, l3;
            float m0 = acc1[0][0] + bxv[0][0];
            float m1 = acc1[0][1] + bxv[0][1];
            float m2 = acc1[0][2] + bxv[0][2];
            float m3 = acc1[0][3] + bxv[0][3];
            tsplit2(m0, m1, h0, l0);
            tsplit2(m2, m3, h1, l1);
            float n0 = acc1[1][0] + bxv[1][0];
            float n1 = acc1[1][1] + bxv[1][1];
            float n2 = acc1[1][2] + bxv[1][2];
            float n3 = acc1[1][3] + bxv[1][3];
            tsplit2(n0, n1, h2, l2);
            tsplit2(n2, n3, h3, l3);
            a2h.u = (u32x4){h0, h1, h2, h3};
            a2l.u = (u32x4){l0, l1, l2, l3};
        }
        f32x4 accL[4];
        #pragma unroll
        for (int g = 0; g < 4; ++g) {
            accL[g] = (f32x4){bsl[g], bsl[g], bsl[g], bsl[g]};
            accL[g] = MFMA(a2h.b, wsp[g], accL[g]);
            accL[g] = MFMA(a2l.b, wsp[g], accL[g]);
        }

        // ---- softmax over 64 g (4 g-frags x 16 lanes) ----
        float mrow[4], srow4[4];
        #pragma unroll
        for (int r = 0; r < 4; ++r)
            mrow[r] = fmaxf(fmaxf(accL[0][r], accL[1][r]), fmaxf(accL[2][r], accL[3][r]));
        #pragma unroll
        for (int d = 1; d <= 8; d <<= 1)
            #pragma unroll
            for (int r = 0; r < 4; ++r)
                mrow[r] = fmaxf(mrow[r], __shfl_xor(mrow[r], d));
        #pragma unroll
        for (int r = 0; r < 4; ++r) {
            float e0 = __expf(accL[0][r] - mrow[r]);
            float e1 = __expf(accL[1][r] - mrow[r]);
            float e2 = __expf(accL[2][r] - mrow[r]);
            float e3 = __expf(accL[3][r] - mrow[r]);
            accL[0][r] = e0; accL[1][r] = e1; accL[2][r] = e2; accL[3][r] = e3;
            srow4[r] = e0 + e1 + e2 + e3;
        }
        #pragma unroll
        for (int d = 1; d <= 8; d <<= 1)
            #pragma unroll
            for (int r = 0; r < 4; ++r)
                srow4[r] += __shfl_xor(srow4[r], d);
        #pragma unroll
        for (int r = 0; r < 4; ++r) {
            const float inv = 1.0f / srow4[r];
            float e0 = accL[0][r] * inv, e1 = accL[1][r] * inv;
            float e2 = accL[2][r] * inv, e3 = accL[3][r] * inv;
            accL[0][r] = e0; accL[1][r] = e1; accL[2][r] = e2; accL[3][r] = e3;
            nacc[0] += e0; nacc[1] += e1; nacc[2] += e2; nacc[3] += e3;
        }

        // ---- P4: pack sw + write image [64 tok][128 col], conflict-free key
        unsigned int pL[4][2];
        #pragma unroll
        for (int fc = 0; fc < 4; ++fc) {
            u16 w0 = f2bf(accL[fc][0]), w1 = f2bf(accL[fc][1]);
            u16 w2 = f2bf(accL[fc][2]), w3 = f2bf(accL[fc][3]);
            pL[fc][0] = (unsigned int)w0 | ((unsigned int)w1 << 16);
            pL[fc][1] = (unsigned int)w2 | ((unsigned int)w3 << 16);
            const int col2 = (hl * 64 + fc * 16 + l15) * 2;
            #pragma unroll
            for (int r = 0; r < 4; ++r) {
                const int tok = tq * 16 + l4 * 4 + r;
                const int key = ((tok >> 2) & 3) << 5;
                const u16 val = (r == 0) ? w0 : (r == 1) ? w1 : (r == 2) ? w2 : w3;
                *(u16*)(lds + LDS_IM + ((tok * 256 + col2) ^ key)) = val;
            }
        }

        // ---- P5: slice_token partial (reg-only, K zero-padded) ----
        unsigned int pF[2][2];
        #pragma unroll
        for (int fc = 0; fc < 2; ++fc) {
            pF[fc][0] = pack2(accF[fc][0], accF[fc][1]);
            pF[fc][1] = pack2(accF[fc][2], accF[fc][3]);
        }
        #pragma unroll
        for (int mt2 = 0; mt2 < 2; ++mt2) {
            union { u32x4 u; bf16x8 b; } a;
            a.u = (u32x4){pF[mt2][0], pF[mt2][1], 0u, 0u};
            #pragma unroll
            for (int nt = 0; nt < 4; ++nt) {
                union { u32x4 u; bf16x8 b; } bb;
                bb.u = (u32x4){pL[nt][0], pL[nt][1], 0u, 0u};
                stacc[mt2][nt] = MFMA(a.b, bb.b, stacc[mt2][nt]);
            }
        }

        __syncthreads();   // B2: image complete (and all GEMM reads done)

        // ---- copy-out image -> global (full-row coverage, coalesced 1KB) --
        #pragma unroll
        for (int q = 0; q < 2; ++q) {
            const int slot = q * 512 + tid;
            const int tok = slot >> 4, sg = slot & 15;
            const int key = ((tok >> 2) & 3) << 5;
            u32x4 v = *(const u32x4*)(lds + LDS_IM + ((tok * 256 + sg * 16) ^ key));
            __builtin_nontemporal_store(v,
                (u32x4*)(swg + (size_t)(tok0 + tok) * 512 + hp * 128 + sg * 8));
        }
    }

    // ---- epilogue: cross-wave (tq) reduction ----
    __syncthreads();
    float* sst = (float*)lds;               // weights region dead: [8][2048]
    float* nst = (float*)(lds + LDS_IM);    // image region: [8][64]
    #pragma unroll
    for (int mt2 = 0; mt2 < 2; ++mt2)
        #pragma unroll
        for (int nt = 0; nt < 4; ++nt)
            #pragma unroll
            for (int r = 0; r < 4; ++r)
                sst[wv * 2048 + (mt2 * 16 + l4 * 4 + r) * 64 + nt * 16 + l15] = stacc[mt2][nt][r];
    #pragma unroll
    for (int fc = 0; fc < 4; ++fc) {
        float v = nacc[fc];
        v += __shfl_xor(v, 16); v += __shfl_xor(v, 32);
        if (l4 == 0) nst[wv * 64 + fc * 16 + l15] = v;
    }
    __syncthreads();
    for (int i = tid; i < 4096; i += 512) {
        const int hl2 = i >> 11, e = i & 2047;
        float s = sst[(hl2 * 4 + 0) * 2048 + e] + sst[(hl2 * 4 + 1) * 2048 + e]
                + sst[(hl2 * 4 + 2) * 2048 + e] + sst[(hl2 * 4 + 3) * 2048 + e];
        __builtin_nontemporal_store(s,
            pst + ((size_t)(hp * 2 + hl2) * 256 + c) * 2048 + e);
    }
    if (tid < 128) {
        const int hl2 = tid >> 6, g = tid & 63;
        float s = nst[(hl2 * 4 + 0) * 64 + g] + nst[(hl2 * 4 + 1) * 64 + g]
                + nst[(hl2 * 4 + 2) * 64 + g] + nst[(hl2 * 4 + 3) * 64 + g];
        pnorm[((size_t)(hp * 2 + hl2) * 256 + c) * 64 + g] = s;
    }
}

// ---------------------------------------------------------------------------
// kC1: blocks 0..127: stn[16384] = sum_chunk pst; blocks 128..131: norm[512]
// ---------------------------------------------------------------------------
__global__ __launch_bounds__(256) void kC1(
    const float* __restrict__ pst, const float* __restrict__ pnorm,
    float* __restrict__ stn, float* __restrict__ norm)
{
    __shared__ float red[256];
    const int tid  = threadIdx.x;
    const int half = tid >> 7;
    const int li   = tid & 127;
    if (blockIdx.x < 128) {
        const int o  = blockIdx.x * 128 + li;
        const int h  = o >> 11, oo = o & 2047;
        float s = 0.f;
        for (int b = half * 128; b < half * 128 + 128; ++b)
            s += __builtin_nontemporal_load(pst + ((size_t)h * 256 + b) * 2048 + oo);
        red[tid] = s;
        __syncthreads();
        if (!half) stn[o] = red[li] + red[li + 128];
    } else {
        const int o = (blockIdx.x - 128) * 128 + li;
        const int h = o >> 6, g = o & 63;
        float s = 0.f;
        for (int b = half * 128; b < half * 128 + 128; ++b)
            s += pnorm[((size_t)h * 256 + b) * 64 + g];
        red[tid] = s;
        __syncthreads();
        if (!half) norm[o] = red[li] + red[li + 128];
    }
}

// ---------------------------------------------------------------------------
// kattn: tiny per-head attention over 64 slice tokens
// ---------------------------------------------------------------------------
__global__ __launch_bounds__(64) void kattn(
    const float* __restrict__ stn, const float* __restrict__ norm,
    const float* __restrict__ Wq, const float* __restrict__ Wk,
    const float* __restrict__ Wv, float* __restrict__ os)
{
    __shared__ float kl[2048], vl[2048];
    const int h = blockIdx.x, g = threadIdx.x;
    const float ng = norm[h * 64 + g] + 1e-5f;
    float s[32];
    #pragma unroll
    for (int d = 0; d < 32; ++d) s[d] = stn[h * 2048 + d * 64 + g] / ng;
    float q[32];
    #pragma unroll
    for (int e = 0; e < 32; ++e) {
        float aq = 0.f, ak = 0.f, av = 0.f;
        #pragma unroll
        for (int d = 0; d < 32; ++d) {
            aq += s[d] * Wq[e * 32 + d];
            ak += s[d] * Wk[e * 32 + d];
            av += s[d] * Wv[e * 32 + d];
        }
        q[e] = aq; kl[g * 32 + e] = ak; vl[g * 32 + e] = av;
    }
    __syncthreads();
    float p[64];
    float mx = -1e30f;
    const float scale = 0.17677669529663689f;
    #pragma unroll
    for (int kk = 0; kk < 64; ++kk) {
        float a = 0.f;
        #pragma unroll
        for (int e = 0; e < 32; ++e) a += q[e] * kl[kk * 32 + e];
        a *= scale; p[kk] = a; mx = fmaxf(mx, a);
    }
    float sum = 0.f;
    #pragma unroll
    for (int kk = 0; kk < 64; ++kk) { p[kk] = __expf(p[kk] - mx); sum += p[kk]; }
    const float inv = 1.0f / sum;
    #pragma unroll
    for (int d = 0; d < 32; ++d) {
        float a = 0.f;
        #pragma unroll
        for (int kk = 0; kk < 64; ++kk) a += p[kk] * inv * vl[kk * 32 + d];
        os[h * 2048 + g * 32 + d] = a;
    }
}

// ---------------------------------------------------------------------------
// kD2: Wc2T[co][hg] = sum_d os[h,g,d] * Wout[co, h*32+d]   (bf16)
// ---------------------------------------------------------------------------
__global__ __launch_bounds__(64) void kD2(
    const float* __restrict__ os, const float* __restrict__ Wout,
    u16* __restrict__ Wc2T)
{
    const int co = blockIdx.x;
    for (int rep = 0; rep < 8; ++rep) {
        const int hg = rep * 64 + threadIdx.x;
        const int h = hg >> 6, g = hg & 63;
        float s = 0.f;
        #pragma unroll
        for (int d = 0; d < 32; ++d)
            s += os[h * 2048 + g * 32 + d] * Wout[co * 256 + h * 32 + d];
        Wc2T[co * 512 + hg] = f2bf(s);
    }
}

// ---------------------------------------------------------------------------
// kE v4 (R10, measured-good): 32-token tiles, grid 512, B hoisted (128 VGPR),
// LDS 64KB = 32K sw stage + 32K y-image, 2 barriers/tile, 2 blocks/CU.
// ---------------------------------------------------------------------------
__global__ __launch_bounds__(512, 2) void kE(
    const u16* __restrict__ swg, const u16* __restrict__ Wc2T,
    const float* __restrict__ bout, float* __restrict__ y)
{
    __shared__ char lds[65536];
    const int tid  = threadIdx.x;
    const int w    = tid >> 6;
    const int lane = tid & 63;
    const int l15  = lane & 15;
    const int l4   = lane >> 4;
    const int aswz = (l15 & 7) << 4;

    const int bid = blockIdx.x;
    const int cnt = 12 + (bid < 106 ? 1 : 0);    // 512*12 + 106 = 6250 tiles
    const long tb = (long)bid * 12 + (bid < 106 ? bid : 106);

    bf16x8 Breg[16][2];
    #pragma unroll
    for (int ks = 0; ks < 16; ++ks)
        #pragma unroll
        for (int fc = 0; fc < 2; ++fc)
            Breg[ks][fc] = *(const bf16x8*)(Wc2T +
                (size_t)(w * 32 + fc * 16 + l15) * 512 + ks * 32 + l4 * 8);

    const float b0 = bout[w * 32 + l15], b1 = bout[w * 32 + 16 + l15];

    u32x4 pf[4];
    #pragma unroll
    for (int k = 0; k < 4; ++k) {
        const int slot = tid + k * 512;
        const int srow = slot >> 6, ss = slot & 63;
        pf[k] = __builtin_nontemporal_load(
            (const u32x4*)(swg + (size_t)(tb * 32 + srow) * 512 + ss * 8));
    }

    for (int t = 0; t < cnt; ++t) {
        const long tok0 = (tb + t) * 32;

        #pragma unroll
        for (int k = 0; k < 4; ++k) {
            const int slot = tid + k * 512;
            const int srow = slot >> 6, ss = slot & 63;
            *(u32x4*)(lds + ((srow * 1024 + ss * 16) ^ ((srow & 7) << 4))) = pf[k];
        }
        __syncthreads();

        if (t + 1 < cnt) {
            #pragma unroll
            for (int k = 0; k < 4; ++k) {
                const int slot = tid + k * 512;
                const int srow = slot >> 6, ss = slot & 63;
                pf[k] = __builtin_nontemporal_load(
                    (const u32x4*)(swg + (size_t)(tok0 + 32 + srow) * 512 + ss * 8));
            }
        }

        f32x4 acc[2][2];
        #pragma unroll
        for (int mt = 0; mt < 2; ++mt) {
            acc[mt][0] = (f32x4){b0, b0, b0, b0};
            acc[mt][1] = (f32x4){b1, b1, b1, b1};
        }

        #pragma unroll
        for (int ks = 0; ks < 16; ++ks) {
            bf16x8 a[2];
            #pragma unroll
            for (int mt = 0; mt < 2; ++mt)
                a[mt] = *(const bf16x8*)(lds + (mt * 16 + l15) * 1024 + ((ks * 64 + l4 * 16) ^ aswz));
            #pragma unroll
            for (int mt = 0; mt < 2; ++mt) {
                acc[mt][0] = MFMA(a[mt], Breg[ks][0], acc[mt][0]);
                acc[mt][1] = MFMA(a[mt], Breg[ks][1], acc[mt][1]);
            }
        }

        #pragma unroll
        for (int mt = 0; mt < 2; ++mt)
            #pragma unroll
            for (int fc = 0; fc < 2; ++fc)
                #pragma unroll
                for (int r = 0; r < 4; ++r) {
                    const int tok = mt * 16 + l4 * 4 + r;
                    const int col = w * 32 + fc * 16 + l15;
                    *(float*)(lds + 32768 + ((tok * 1024 + col * 4) ^ ((tok & 7) << 4))) =
                        acc[mt][fc][r];
                }
        __syncthreads();

        #pragma unroll
        for (int k = 0; k < 4; ++k) {
            const int slot = tid + k * 512;
            const int yrow = slot >> 6, ys = slot & 63;
            u32x4 v = *(const u32x4*)(lds + 32768 + ((yrow * 1024 + ys * 16) ^ ((yrow & 7) << 4)));
            __builtin_nontemporal_store(v,
                (u32x4*)(y + (size_t)(tok0 + yrow) * 256 + ys * 4));
        }
    }
}

// ---------------------------------------------------------------------------
extern "C" void kernel_launch(void* const* d_in, const int* in_sizes, int n_in,
                              void* d_out, int out_size, void* d_ws, size_t ws_size,
                              hipStream_t stream) {
    const float* x       = (const float*)d_in[0];
    const float* Wx      = (const float*)d_in[1];
    const float* bx      = (const float*)d_in[2];
    const float* Wfx     = (const float*)d_in[3];
    const float* bfx     = (const float*)d_in[4];
    const float* Wslice  = (const float*)d_in[5];
    const float* bslice  = (const float*)d_in[6];
    const float* Wq      = (const float*)d_in[7];
    const float* Wk      = (const float*)d_in[8];
    const float* Wv      = (const float*)d_in[9];
    const float* Wout    = (const float*)d_in[10];
    const float* bout    = (const float*)d_in[11];
    const float* temp    = (const float*)d_in[12];

    char* wsb = (char*)d_ws;
    u16*   sw    = (u16*)(wsb);                      // 204,800,000 B
    float* pst   = (float*)(wsb + 204800000);        //  16,777,216 B
    float* pnorm = (float*)(wsb + 238354432);        //     524,288 B
    u16*   WxTb  = (u16*)(wsb + 239403008);          //     131,072 B
    u16*   WfxTg = (u16*)(wsb + 239534080);          //     131,072 B
    u16*   WsP   = (u16*)(wsb + 239665152);          //      32,768 B
    float* bslv  = (float*)(wsb + 239697920);        //       2,048 B
    u16*   Wc2T  = (u16*)(wsb + 239798272);          //     262,144 B
    float* os    = (float*)(wsb + 240060416);        //      65,536 B
    float* stn   = (float*)(wsb + 240125952);        //      65,536 B
    float* norm  = (float*)(wsb + 240191488);        //       2,048 B
    float* y     = (float*)d_out;

    kprep<<<578, 256, 0, stream>>>(Wx, Wfx, Wslice, bslice, temp, WxTb, WfxTg, WsP, bslv);
    kAB<<<1024, 512, 0, stream>>>(x, WxTb, WfxTg, WsP, bx, bfx, bslv, sw, pst, pnorm);
    kC1<<<132, 256, 0, stream>>>(pst, pnorm, stn, norm);
    kattn<<<8, 64, 0, stream>>>(stn, norm, Wq, Wk, Wv, os);
    kD2<<<256, 64, 0, stream>>>(os, Wout, Wc2T);
    kE<<<512, 512, 0, stream>>>(sw, Wc2T, bout, y);
}